// Round 2
// baseline (2170.948 us; speedup 1.0000x reference)
//
#include <hip/hip_runtime.h>
#include <math.h>

#define S_LEN 2048
#define NH 16
#define HDIM 64
#define BATCH 2
#define BHC 32          // BATCH*NH
#define KK 409          // int(2048 * (1.0 - 0.8)) per reference float math
#define DMODEL 1024
#define MROWS 4096      // BATCH*S_LEN

__device__ __forceinline__ unsigned f2ord(float f) {
    unsigned u = __float_as_uint(f);
    return (u & 0x80000000u) ? ~u : (u | 0x80000000u);
}

// ---------------------------------------------------------------------------
// C = A @ W^T + bias.  A: [4096,1024] row-major, W: [N=1024, K=1024] row-major.
// headsplit==1: write out[b,h,s,hd]  (n = h*64+hd, m = b*2048+s)
// headsplit==0: write out[m,n] plain row-major
// Tile: 128(M) x 64(N), BK=16, 256 threads, 8x4 micro-tile per thread.
// ---------------------------------------------------------------------------
__global__ __launch_bounds__(256)
void gemm_nt(const float* __restrict__ A, const float* __restrict__ W,
             const float* __restrict__ bias, float* __restrict__ out,
             int headsplit)
{
    __shared__ __align__(16) float As[16][132];
    __shared__ __align__(16) float Ws[16][68];
    const int tid = threadIdx.x;
    const int n0 = blockIdx.x * 64;
    const int m0 = blockIdx.y * 128;
    const int tx = tid & 15;
    const int ty = tid >> 4;

    float acc[8][4];
#pragma unroll
    for (int i = 0; i < 8; ++i)
#pragma unroll
        for (int j = 0; j < 4; ++j) acc[i][j] = 0.f;

    const int arow = tid >> 2;
    const int akq  = (tid & 3) * 4;

    for (int k0 = 0; k0 < 1024; k0 += 16) {
        const float4 av0 = *(const float4*)(A + (size_t)(m0 + arow) * 1024 + k0 + akq);
        const float4 av1 = *(const float4*)(A + (size_t)(m0 + arow + 64) * 1024 + k0 + akq);
        const float4 wv  = *(const float4*)(W + (size_t)(n0 + arow) * 1024 + k0 + akq);
        __syncthreads();
        As[akq + 0][arow] = av0.x; As[akq + 1][arow] = av0.y;
        As[akq + 2][arow] = av0.z; As[akq + 3][arow] = av0.w;
        As[akq + 0][arow + 64] = av1.x; As[akq + 1][arow + 64] = av1.y;
        As[akq + 2][arow + 64] = av1.z; As[akq + 3][arow + 64] = av1.w;
        Ws[akq + 0][arow] = wv.x; Ws[akq + 1][arow] = wv.y;
        Ws[akq + 2][arow] = wv.z; Ws[akq + 3][arow] = wv.w;
        __syncthreads();
#pragma unroll
        for (int kk = 0; kk < 16; ++kk) {
            const float4 a0 = *(const float4*)&As[kk][ty * 8];
            const float4 a1 = *(const float4*)&As[kk][ty * 8 + 4];
            const float4 bv = *(const float4*)&Ws[kk][tx * 4];
            const float a[8] = {a0.x, a0.y, a0.z, a0.w, a1.x, a1.y, a1.z, a1.w};
            const float b[4] = {bv.x, bv.y, bv.z, bv.w};
#pragma unroll
            for (int i = 0; i < 8; ++i)
#pragma unroll
                for (int j = 0; j < 4; ++j) acc[i][j] += a[i] * b[j];
        }
    }

    const int nb = n0 + tx * 4;
    const float4 b4 = *(const float4*)(bias + nb);
#pragma unroll
    for (int i = 0; i < 8; ++i) {
        const int m = m0 + ty * 8 + i;
        float4 o;
        o.x = acc[i][0] + b4.x; o.y = acc[i][1] + b4.y;
        o.z = acc[i][2] + b4.z; o.w = acc[i][3] + b4.w;
        if (headsplit) {
            const int b = m >> 11, s = m & 2047;
            const int h = nb >> 6, hd = nb & 63;
            *(float4*)(out + ((size_t)((b * NH + h) * S_LEN + s)) * HDIM + hd) = o;
        } else {
            *(float4*)(out + (size_t)m * 1024 + nb) = o;
        }
    }
}

// ---------------------------------------------------------------------------
// K[bh,s,hd] -> Kt[bh,hd,s]
// ---------------------------------------------------------------------------
__global__ __launch_bounds__(256)
void transpose_k(const float* __restrict__ K, float* __restrict__ Kt)
{
    __shared__ float t[64][65];
    const int tid = threadIdx.x;
    const int s0 = blockIdx.x * 64;
    const int bh = blockIdx.y;
    const float* Kb = K + (size_t)bh * S_LEN * HDIM;
#pragma unroll
    for (int i = 0; i < 4; ++i) {
        const int f = tid + i * 256;
        const int s = f >> 4;
        const int hq = (f & 15) * 4;
        const float4 v = *(const float4*)(Kb + (size_t)(s0 + s) * HDIM + hq);
        t[s][hq + 0] = v.x; t[s][hq + 1] = v.y; t[s][hq + 2] = v.z; t[s][hq + 3] = v.w;
    }
    __syncthreads();
    float* Ktb = Kt + (size_t)bh * HDIM * S_LEN;
#pragma unroll
    for (int i = 0; i < 4; ++i) {
        const int f = tid + i * 256;
        const int hd = f >> 4;
        const int sq = (f & 15) * 4;
        float4 v;
        v.x = t[sq + 0][hd]; v.y = t[sq + 1][hd];
        v.z = t[sq + 2][hd]; v.w = t[sq + 3][hd];
        *(float4*)(Ktb + (size_t)hd * S_LEN + s0 + sq) = v;
    }
}

// ---------------------------------------------------------------------------
// Fused attention v2: block = (b,h) x 8 query rows, 512 threads (8 waves).
// Scores: register-tiled — wave w owns key-span [w*256, w*256+256); each lane
// holds an 8-row x 4-col fp32 accumulator, reads each Kt float4 exactly once
// (coalesced, L2 traffic 4 GB total vs 32 GB in v1).
// Then per-wave-per-row: exact radix select (409th largest) -> softmax over
// kept set -> compacted PV gather -> AO[b,s,h*64+hd].
// Dynamic LDS: sc 64K + qs 2K + (hist 8K overlaid with idxl 8K) + ctrl ~ 76 KB
// -> 2 blocks/CU, 16 waves/CU.
// ---------------------------------------------------------------------------
__global__ __launch_bounds__(512)
void attn_kernel(const float* __restrict__ Q, const float* __restrict__ Kt,
                 const float* __restrict__ V, float* __restrict__ AO)
{
    extern __shared__ __align__(16) char smem[];
    float* sc = (float*)smem;                         // [8][2048]  64 KB
    float* qs = sc + 8 * 2048;                        // [8][64]     2 KB
    int*   hist = (int*)(qs + 8 * 64);                // [8][256]    8 KB
    unsigned short* idxl = (unsigned short*)hist;     // [8][512] overlay 8 KB
    int* ctrl = (int*)(smem + (8 * 2048 + 8 * 64) * 4 + 8192);
    int* sel_d   = ctrl;                              // [8]
    int* sel_rem = ctrl + 8;                          // [8]
    int* kcount  = ctrl + 16;                         // [8]

    const int tid  = threadIdx.x;
    const int lane = tid & 63;
    const int w    = tid >> 6;        // wave id == row id in select/PV phases

    // XCD swizzle: 8 XCDs x 4 heads each -> per-XCD K/V working set ~4MB (L2)
    const int blk = blockIdx.x;
    const int xcd = blk & 7;
    const int idx = blk >> 3;              // 0..1023
    const int bh  = xcd * 4 + (idx & 3);   // 0..31
    const int q0  = (idx >> 2) * 8;        // 0..2040

    {   // load 8 Q rows (512 floats, one per thread)
        const int r = tid >> 6, d = tid & 63;
        qs[r * 64 + d] = Q[((size_t)bh * S_LEN + q0 + r) * HDIM + d];
    }
    if (tid < 8) kcount[tid] = 0;
    __syncthreads();

    // ---- scores: register-tiled.  wave w covers j in [w*256, w*256+256),
    //      lane covers 4 consecutive j; acc[8 rows][4 cols] ----
    {
        const int j0 = w * 256 + lane * 4;
        const float* kp = Kt + (size_t)bh * HDIM * S_LEN + j0;
        float acc[8][4];
#pragma unroll
        for (int r = 0; r < 8; ++r)
#pragma unroll
            for (int c = 0; c < 4; ++c) acc[r][c] = 0.f;

        for (int d0 = 0; d0 < 64; d0 += 4) {
            float4 kv0 = *(const float4*)(kp + (size_t)(d0 + 0) * S_LEN);
            float4 kv1 = *(const float4*)(kp + (size_t)(d0 + 1) * S_LEN);
            float4 kv2 = *(const float4*)(kp + (size_t)(d0 + 2) * S_LEN);
            float4 kv3 = *(const float4*)(kp + (size_t)(d0 + 3) * S_LEN);
#pragma unroll
            for (int r = 0; r < 8; ++r) {
                const float4 q4 = *(const float4*)&qs[r * 64 + d0];
                acc[r][0] += q4.x * kv0.x + q4.y * kv1.x + q4.z * kv2.x + q4.w * kv3.x;
                acc[r][1] += q4.x * kv0.y + q4.y * kv1.y + q4.z * kv2.y + q4.w * kv3.y;
                acc[r][2] += q4.x * kv0.z + q4.y * kv1.z + q4.z * kv2.z + q4.w * kv3.z;
                acc[r][3] += q4.x * kv0.w + q4.y * kv1.w + q4.z * kv2.w + q4.w * kv3.w;
            }
        }
#pragma unroll
        for (int r = 0; r < 8; ++r) {
            float4 o;
            o.x = acc[r][0] * 0.125f; o.y = acc[r][1] * 0.125f;
            o.z = acc[r][2] * 0.125f; o.w = acc[r][3] * 0.125f;
            *(float4*)&sc[r * 2048 + j0] = o;
        }
    }
    __syncthreads();

    // ---- exact 409th-largest via 4-pass radix select (wave w -> row w) ----
    const int r = w;
    float* scr = sc + r * 2048;
    int* hr = hist + r * 256;
    unsigned pref = 0;
    int remaining = KK;
    for (int pass = 0; pass < 4; ++pass) {
        const int shift = 24 - 8 * pass;
#pragma unroll
        for (int i = 0; i < 4; ++i) hr[lane * 4 + i] = 0;
        __syncthreads();
        for (int i = 0; i < 32; ++i) {
            const unsigned u = f2ord(scr[i * 64 + lane]);
            const bool match = (pass == 0) || ((u >> (shift + 8)) == pref);
            if (match) atomicAdd(&hr[(u >> shift) & 255], 1);
        }
        __syncthreads();
        const int c0 = hr[lane * 4 + 0], c1 = hr[lane * 4 + 1];
        const int c2 = hr[lane * 4 + 2], c3 = hr[lane * 4 + 3];
        const int tot = c0 + c1 + c2 + c3;
        int suf = tot;
#pragma unroll
        for (int off = 1; off < 64; off <<= 1) {
            const int o = __shfl_down(suf, off);
            if (lane + off < 64) suf += o;
        }
        const int above3 = suf - tot;
        const int above2 = above3 + c3;
        const int above1 = above2 + c2;
        const int above0 = above1 + c1;
        if (above3 < remaining && remaining <= above3 + c3) { sel_d[r] = lane * 4 + 3; sel_rem[r] = remaining - above3; }
        if (above2 < remaining && remaining <= above2 + c2) { sel_d[r] = lane * 4 + 2; sel_rem[r] = remaining - above2; }
        if (above1 < remaining && remaining <= above1 + c1) { sel_d[r] = lane * 4 + 1; sel_rem[r] = remaining - above1; }
        if (above0 < remaining && remaining <= above0 + c0) { sel_d[r] = lane * 4 + 0; sel_rem[r] = remaining - above0; }
        __syncthreads();
        pref = (pref << 8) | (unsigned)sel_d[r];
        remaining = sel_rem[r];
        __syncthreads();
    }
    const unsigned T = pref;   // ordered-bit pattern of the 409th largest

    // ---- row max ----
    float mx = -1e30f;
    for (int i = 0; i < 32; ++i) mx = fmaxf(mx, scr[i * 64 + lane]);
#pragma unroll
    for (int off = 32; off >= 1; off >>= 1) mx = fmaxf(mx, __shfl_xor(mx, off));

    // ---- exp over kept set + compact index list ----
    unsigned short* il = idxl + r * 512;
    float lsum = 0.f;
    for (int i = 0; i < 32; ++i) {
        const int j = i * 64 + lane;
        const float s = scr[j];
        float e = 0.f;
        if (f2ord(s) >= T) {
            e = __expf(s - mx);
            const int slot = atomicAdd(&kcount[r], 1);
            if (slot < 512) il[slot] = (unsigned short)j;
        }
        scr[j] = e;
        lsum += e;
    }
#pragma unroll
    for (int off = 32; off >= 1; off >>= 1) lsum += __shfl_xor(lsum, off);
    const float invd = 1.f / lsum;
    __syncthreads();

    // ---- PV: out[r, 0..63] = sum_j p_j * V[j, :]  (4 j-partitions/wave) ----
    const int kept = kcount[r];
    const int p  = lane >> 4;
    const int dq = lane & 15;
    const float* Vb = V + (size_t)bh * S_LEN * HDIM;
    float ox = 0.f, oy = 0.f, oz = 0.f, ow = 0.f;
    if (kept <= 512) {
        for (int t = p; t < kept; t += 4) {
            const int j = il[t];
            const float sp = scr[j];
            const float4 vv = *(const float4*)(Vb + (size_t)j * HDIM + dq * 4);
            ox += sp * vv.x; oy += sp * vv.y; oz += sp * vv.z; ow += sp * vv.w;
        }
    } else {   // pathological tie overflow: dense fallback (correct, slow)
        for (int j = p * 512; j < p * 512 + 512; ++j) {
            const float sp = scr[j];
            if (sp != 0.f) {
                const float4 vv = *(const float4*)(Vb + (size_t)j * HDIM + dq * 4);
                ox += sp * vv.x; oy += sp * vv.y; oz += sp * vv.z; ow += sp * vv.w;
            }
        }
    }
#pragma unroll
    for (int off = 16; off <= 32; off <<= 1) {
        ox += __shfl_xor(ox, off);
        oy += __shfl_xor(oy, off);
        oz += __shfl_xor(oz, off);
        ow += __shfl_xor(ow, off);
    }
    if (lane < 16) {
        const int b = bh >> 4, h = bh & 15;
        float4 o;
        o.x = ox * invd; o.y = oy * invd; o.z = oz * invd; o.w = ow * invd;
        *(float4*)(AO + ((size_t)(b * S_LEN + q0 + r)) * DMODEL + h * HDIM + dq * 4) = o;
    }
}

// ---------------------------------------------------------------------------
extern "C" void kernel_launch(void* const* d_in, const int* in_sizes, int n_in,
                              void* d_out, int out_size, void* d_ws, size_t ws_size,
                              hipStream_t stream)
{
    const float* X  = (const float*)d_in[0];
    const float* Wq = (const float*)d_in[1];
    const float* bq = (const float*)d_in[2];
    const float* Wk = (const float*)d_in[3];
    const float* bk = (const float*)d_in[4];
    const float* Wv = (const float*)d_in[5];
    const float* bv = (const float*)d_in[6];
    const float* Wo = (const float*)d_in[7];
    const float* bo = (const float*)d_in[8];

    float* ws = (float*)d_ws;
    const size_t SEG = (size_t)BHC * S_LEN * HDIM;  // 4,194,304 floats = 16 MB
    float* Qb  = ws;
    float* Kb  = ws + SEG;
    float* Ktb = ws + 2 * SEG;
    float* Vb  = ws + 3 * SEG;
    float* AO  = ws + 4 * SEG;   // [B,S,D]

    // dynamic LDS for attn: sc 64K + qs 2K + hist/idxl 8K + ctrl
    const int attn_lds = (8 * 2048 + 8 * 64) * 4 + 8192 + 96;
    static int lds_set = 0;
    if (!lds_set) {
        hipFuncSetAttribute((const void*)attn_kernel,
                            hipFuncAttributeMaxDynamicSharedMemorySize, attn_lds);
        lds_set = 1;
    }

    const dim3 ggrid(16, 32, 1);
    gemm_nt<<<ggrid, 256, 0, stream>>>(X, Wq, bq, Qb, 1);
    gemm_nt<<<ggrid, 256, 0, stream>>>(X, Wk, bk, Kb, 1);
    gemm_nt<<<ggrid, 256, 0, stream>>>(X, Wv, bv, Vb, 1);
    transpose_k<<<dim3(32, 32, 1), 256, 0, stream>>>(Kb, Ktb);
    attn_kernel<<<8192, 512, attn_lds, stream>>>(Qb, Ktb, Vb, AO);
    gemm_nt<<<ggrid, 256, 0, stream>>>(AO, Wo, bo, (float*)d_out, 0);
}

// Round 3
// 1633.811 us; speedup vs baseline: 1.3288x; 1.3288x over previous
//
#include <hip/hip_runtime.h>
#include <math.h>

#define S_LEN 2048
#define NH 16
#define HDIM 64
#define BATCH 2
#define BHC 32          // BATCH*NH
#define KK 409          // int(2048 * (1.0 - 0.8)) per reference float math
#define DMODEL 1024
#define MROWS 4096      // BATCH*S_LEN

__device__ __forceinline__ unsigned f2ord(float f) {
    unsigned u = __float_as_uint(f);
    return (u & 0x80000000u) ? ~u : (u | 0x80000000u);
}
__device__ __forceinline__ float ord2f(unsigned v) {
    unsigned u = (v & 0x80000000u) ? (v & 0x7fffffffu) : ~v;
    return __uint_as_float(u);
}

// ---------------------------------------------------------------------------
// C = A @ W^T + bias.  A: [4096,1024] row-major, W: [N=1024, K=1024] row-major.
// headsplit==1: write out[b,h,s,hd]  (n = h*64+hd, m = b*2048+s)
// headsplit==0: write out[m,n] plain row-major
// ---------------------------------------------------------------------------
__global__ __launch_bounds__(256)
void gemm_nt(const float* __restrict__ A, const float* __restrict__ W,
             const float* __restrict__ bias, float* __restrict__ out,
             int headsplit)
{
    __shared__ __align__(16) float As[16][132];
    __shared__ __align__(16) float Ws[16][68];
    const int tid = threadIdx.x;
    const int n0 = blockIdx.x * 64;
    const int m0 = blockIdx.y * 128;
    const int tx = tid & 15;
    const int ty = tid >> 4;

    float acc[8][4];
#pragma unroll
    for (int i = 0; i < 8; ++i)
#pragma unroll
        for (int j = 0; j < 4; ++j) acc[i][j] = 0.f;

    const int arow = tid >> 2;
    const int akq  = (tid & 3) * 4;

    for (int k0 = 0; k0 < 1024; k0 += 16) {
        const float4 av0 = *(const float4*)(A + (size_t)(m0 + arow) * 1024 + k0 + akq);
        const float4 av1 = *(const float4*)(A + (size_t)(m0 + arow + 64) * 1024 + k0 + akq);
        const float4 wv  = *(const float4*)(W + (size_t)(n0 + arow) * 1024 + k0 + akq);
        __syncthreads();
        As[akq + 0][arow] = av0.x; As[akq + 1][arow] = av0.y;
        As[akq + 2][arow] = av0.z; As[akq + 3][arow] = av0.w;
        As[akq + 0][arow + 64] = av1.x; As[akq + 1][arow + 64] = av1.y;
        As[akq + 2][arow + 64] = av1.z; As[akq + 3][arow + 64] = av1.w;
        Ws[akq + 0][arow] = wv.x; Ws[akq + 1][arow] = wv.y;
        Ws[akq + 2][arow] = wv.z; Ws[akq + 3][arow] = wv.w;
        __syncthreads();
#pragma unroll
        for (int kk = 0; kk < 16; ++kk) {
            const float4 a0 = *(const float4*)&As[kk][ty * 8];
            const float4 a1 = *(const float4*)&As[kk][ty * 8 + 4];
            const float4 bv = *(const float4*)&Ws[kk][tx * 4];
            const float a[8] = {a0.x, a0.y, a0.z, a0.w, a1.x, a1.y, a1.z, a1.w};
            const float b[4] = {bv.x, bv.y, bv.z, bv.w};
#pragma unroll
            for (int i = 0; i < 8; ++i)
#pragma unroll
                for (int j = 0; j < 4; ++j) acc[i][j] += a[i] * b[j];
        }
    }

    const int nb = n0 + tx * 4;
    const float4 b4 = *(const float4*)(bias + nb);
#pragma unroll
    for (int i = 0; i < 8; ++i) {
        const int m = m0 + ty * 8 + i;
        float4 o;
        o.x = acc[i][0] + b4.x; o.y = acc[i][1] + b4.y;
        o.z = acc[i][2] + b4.z; o.w = acc[i][3] + b4.w;
        if (headsplit) {
            const int b = m >> 11, s = m & 2047;
            const int h = nb >> 6, hd = nb & 63;
            *(float4*)(out + ((size_t)((b * NH + h) * S_LEN + s)) * HDIM + hd) = o;
        } else {
            *(float4*)(out + (size_t)m * 1024 + nb) = o;
        }
    }
}

// ---------------------------------------------------------------------------
// K[bh,s,hd] -> Kt[bh,hd,s]
// ---------------------------------------------------------------------------
__global__ __launch_bounds__(256)
void transpose_k(const float* __restrict__ K, float* __restrict__ Kt)
{
    __shared__ float t[64][65];
    const int tid = threadIdx.x;
    const int s0 = blockIdx.x * 64;
    const int bh = blockIdx.y;
    const float* Kb = K + (size_t)bh * S_LEN * HDIM;
#pragma unroll
    for (int i = 0; i < 4; ++i) {
        const int f = tid + i * 256;
        const int s = f >> 4;
        const int hq = (f & 15) * 4;
        const float4 v = *(const float4*)(Kb + (size_t)(s0 + s) * HDIM + hq);
        t[s][hq + 0] = v.x; t[s][hq + 1] = v.y; t[s][hq + 2] = v.z; t[s][hq + 3] = v.w;
    }
    __syncthreads();
    float* Ktb = Kt + (size_t)bh * HDIM * S_LEN;
#pragma unroll
    for (int i = 0; i < 4; ++i) {
        const int f = tid + i * 256;
        const int hd = f >> 4;
        const int sq = (f & 15) * 4;
        float4 v;
        v.x = t[sq + 0][hd]; v.y = t[sq + 1][hd];
        v.z = t[sq + 2][hd]; v.w = t[sq + 3][hd];
        *(float4*)(Ktb + (size_t)hd * S_LEN + s0 + sq) = v;
    }
}

// ---------------------------------------------------------------------------
// Fused attention v3: block = (b,h) x 8 query rows, 512 threads (8 waves).
// Scores: register-tiled (wave w owns key-span [w*256,w*256+256), 8x4 acc).
// Select/softmax/compact: wave w owns row w entirely in registers —
//   * exact k-th-largest via 32-step binary radix select on ordered uints
//     (pure VALU + shuffle reduce; NO LDS atomics, NO histogram)
//   * row max = integer max of ordered uints
//   * ballot-based compaction (NO atomics)
// Only 2 __syncthreads per block; everything after the score barrier is
// wave-independent.  LDS: sc 64K + qs 2K + il 8K = 74 KB -> 2 blocks/CU.
// ---------------------------------------------------------------------------
__global__ __launch_bounds__(512, 4)
void attn_kernel(const float* __restrict__ Q, const float* __restrict__ Kt,
                 const float* __restrict__ V, float* __restrict__ AO)
{
    extern __shared__ __align__(16) char smem[];
    float* sc = (float*)smem;                              // [8][2048]  64 KB
    float* qs = sc + 8 * 2048;                             // [8][64]     2 KB
    unsigned short* idxl = (unsigned short*)(qs + 8 * 64); // [8][512]    8 KB

    const int tid  = threadIdx.x;
    const int lane = tid & 63;
    const int w    = tid >> 6;        // wave id == row id after score phase

    // XCD swizzle: 8 XCDs x 4 heads each -> per-XCD K/V working set ~4MB (L2)
    const int blk = blockIdx.x;
    const int xcd = blk & 7;
    const int idx = blk >> 3;              // 0..1023
    const int bh  = xcd * 4 + (idx & 3);   // 0..31
    const int q0  = (idx >> 2) * 8;        // 0..2040

    {   // load 8 Q rows (512 floats, one per thread)
        const int r = tid >> 6, d = tid & 63;
        qs[r * 64 + d] = Q[((size_t)bh * S_LEN + q0 + r) * HDIM + d];
    }
    __syncthreads();

    // ---- scores: wave w covers j in [w*256, w*256+256), lane covers 4 j ----
    {
        const int j0 = w * 256 + lane * 4;
        const float* kp = Kt + (size_t)bh * HDIM * S_LEN + j0;
        float acc[8][4];
#pragma unroll
        for (int r = 0; r < 8; ++r)
#pragma unroll
            for (int c = 0; c < 4; ++c) acc[r][c] = 0.f;

        for (int d0 = 0; d0 < 64; d0 += 4) {
            float4 kv0 = *(const float4*)(kp + (size_t)(d0 + 0) * S_LEN);
            float4 kv1 = *(const float4*)(kp + (size_t)(d0 + 1) * S_LEN);
            float4 kv2 = *(const float4*)(kp + (size_t)(d0 + 2) * S_LEN);
            float4 kv3 = *(const float4*)(kp + (size_t)(d0 + 3) * S_LEN);
#pragma unroll
            for (int r = 0; r < 8; ++r) {
                const float4 q4 = *(const float4*)&qs[r * 64 + d0];
                acc[r][0] += q4.x * kv0.x + q4.y * kv1.x + q4.z * kv2.x + q4.w * kv3.x;
                acc[r][1] += q4.x * kv0.y + q4.y * kv1.y + q4.z * kv2.y + q4.w * kv3.y;
                acc[r][2] += q4.x * kv0.z + q4.y * kv1.z + q4.z * kv2.z + q4.w * kv3.z;
                acc[r][3] += q4.x * kv0.w + q4.y * kv1.w + q4.z * kv2.w + q4.w * kv3.w;
            }
        }
#pragma unroll
        for (int r = 0; r < 8; ++r) {
            float4 o;
            o.x = acc[r][0] * 0.125f; o.y = acc[r][1] * 0.125f;
            o.z = acc[r][2] * 0.125f; o.w = acc[r][3] * 0.125f;
            *(float4*)&sc[r * 2048 + j0] = o;
        }
    }
    __syncthreads();
    // -------- from here on, wave w exclusively owns row w: no barriers --------

    const int r = w;
    float* scr = sc + r * 2048;
    unsigned short* il = idxl + r * 512;

    // ---- load row into registers as ordered uints (conflict-free strided) ----
    unsigned u[32];
#pragma unroll
    for (int i = 0; i < 32; ++i) u[i] = f2ord(scr[i * 64 + lane]);

    // ---- exact 409th-largest: 32-step binary radix select, all-register ----
    unsigned T = 0;
    int rem = KK;
    for (int b = 31; b >= 0; --b) {
        const unsigned want = (T >> b) | 1u;
        int cnt = 0;
#pragma unroll
        for (int i = 0; i < 32; ++i) cnt += ((u[i] >> b) == want) ? 1 : 0;
#pragma unroll
        for (int off = 32; off >= 1; off >>= 1) cnt += __shfl_xor(cnt, off);
        if (cnt >= rem) T |= (1u << b);
        else rem -= cnt;
    }
    // T = ordered-bit pattern of the k-th largest; keep set = { u >= T }
    // (ties at T all kept, matching reference's `attn < thr` masking)

    // ---- row max (integer max of ordered uints == float max) ----
    unsigned umx = 0;
#pragma unroll
    for (int i = 0; i < 32; ++i) umx = u[i] > umx ? u[i] : umx;
#pragma unroll
    for (int off = 32; off >= 1; off >>= 1) {
        const unsigned o = (unsigned)__shfl_xor((int)umx, off);
        umx = o > umx ? o : umx;
    }
    const float mx = ord2f(umx);

    // ---- exp over kept set + ballot compaction (no atomics) ----
    int base = 0;
    float lsum = 0.f;
#pragma unroll
    for (int i = 0; i < 32; ++i) {
        const int j = i * 64 + lane;
        const bool keep = (u[i] >= T);
        float e = 0.f;
        if (keep) e = __expf(ord2f(u[i]) - mx);
        scr[j] = e;
        const unsigned long long msk = __ballot(keep);
        if (keep) {
            const int pos = base + __builtin_popcountll(msk & ((1ull << lane) - 1ull));
            if (pos < 512) il[pos] = (unsigned short)j;
        }
        base += __builtin_popcountll(msk);
        lsum += e;
    }
#pragma unroll
    for (int off = 32; off >= 1; off >>= 1) lsum += __shfl_xor(lsum, off);
    const float invd = 1.f / lsum;
    const int kept = base;

    // ---- PV: out[r, 0..63] = sum_j p_j * V[j, :]  (4 j-partitions/wave) ----
    const int p  = lane >> 4;
    const int dq = lane & 15;
    const float* Vb = V + (size_t)bh * S_LEN * HDIM;
    float ox = 0.f, oy = 0.f, oz = 0.f, ow = 0.f;
    if (kept <= 512) {
        for (int t = p; t < kept; t += 4) {
            const int j = il[t];
            const float sp = scr[j];
            const float4 vv = *(const float4*)(Vb + (size_t)j * HDIM + dq * 4);
            ox += sp * vv.x; oy += sp * vv.y; oz += sp * vv.z; ow += sp * vv.w;
        }
    } else {   // pathological tie overflow: dense fallback (correct, slow)
        for (int j = p * 512; j < p * 512 + 512; ++j) {
            const float sp = scr[j];
            if (sp != 0.f) {
                const float4 vv = *(const float4*)(Vb + (size_t)j * HDIM + dq * 4);
                ox += sp * vv.x; oy += sp * vv.y; oz += sp * vv.z; ow += sp * vv.w;
            }
        }
    }
#pragma unroll
    for (int off = 16; off <= 32; off <<= 1) {
        ox += __shfl_xor(ox, off);
        oy += __shfl_xor(oy, off);
        oz += __shfl_xor(oz, off);
        ow += __shfl_xor(ow, off);
    }
    if (lane < 16) {
        const int b = bh >> 4, h = bh & 15;
        float4 o;
        o.x = ox * invd; o.y = oy * invd; o.z = oz * invd; o.w = ow * invd;
        *(float4*)(AO + ((size_t)(b * S_LEN + q0 + r)) * DMODEL + h * HDIM + dq * 4) = o;
    }
}

// ---------------------------------------------------------------------------
extern "C" void kernel_launch(void* const* d_in, const int* in_sizes, int n_in,
                              void* d_out, int out_size, void* d_ws, size_t ws_size,
                              hipStream_t stream)
{
    const float* X  = (const float*)d_in[0];
    const float* Wq = (const float*)d_in[1];
    const float* bq = (const float*)d_in[2];
    const float* Wk = (const float*)d_in[3];
    const float* bk = (const float*)d_in[4];
    const float* Wv = (const float*)d_in[5];
    const float* bv = (const float*)d_in[6];
    const float* Wo = (const float*)d_in[7];
    const float* bo = (const float*)d_in[8];

    float* ws = (float*)d_ws;
    const size_t SEG = (size_t)BHC * S_LEN * HDIM;  // 4,194,304 floats = 16 MB
    float* Qb  = ws;
    float* Kb  = ws + SEG;
    float* Ktb = ws + 2 * SEG;
    float* Vb  = ws + 3 * SEG;
    float* AO  = ws + 4 * SEG;   // [B,S,D]

    // dynamic LDS for attn: sc 64K + qs 2K + il 8K = 74 KB -> 2 blocks/CU
    const int attn_lds = (8 * 2048 + 8 * 64) * 4 + 8 * 512 * 2;
    hipFuncSetAttribute((const void*)attn_kernel,
                        hipFuncAttributeMaxDynamicSharedMemorySize, attn_lds);

    const dim3 ggrid(16, 32, 1);
    gemm_nt<<<ggrid, 256, 0, stream>>>(X, Wq, bq, Qb, 1);
    gemm_nt<<<ggrid, 256, 0, stream>>>(X, Wk, bk, Kb, 1);
    gemm_nt<<<ggrid, 256, 0, stream>>>(X, Wv, bv, Vb, 1);
    transpose_k<<<dim3(32, 32, 1), 256, 0, stream>>>(Kb, Ktb);
    attn_kernel<<<8192, 512, attn_lds, stream>>>(Qb, Ktb, Vb, AO);
    gemm_nt<<<ggrid, 256, 0, stream>>>(AO, Wo, bo, (float*)d_out, 0);
}

// Round 4
// 1477.903 us; speedup vs baseline: 1.4689x; 1.1055x over previous
//
#include <hip/hip_runtime.h>
#include <math.h>

#define S_LEN 2048
#define NH 16
#define HDIM 64
#define BATCH 2
#define BHC 32          // BATCH*NH
#define KK 409          // int(2048 * (1.0 - 0.8)) per reference float math
#define DMODEL 1024

typedef __attribute__((ext_vector_type(8))) short bf16x8;   // 8 bf16 in 4 VGPRs
typedef __attribute__((ext_vector_type(4))) float f32x4;

#define SC_STR 2052     // fp32 score row stride (pad: (4q+key)%32 -> 2-way, free)
#define P_STR  2056     // bf16 P row stride (16B-aligned rows)
#define QS_STR 72       // Q LDS row stride in bf16 (pad for B-frag reads)

__device__ __forceinline__ unsigned f2ord(float f) {
    unsigned u = __float_as_uint(f);
    return (u & 0x80000000u) ? ~u : (u | 0x80000000u);
}
__device__ __forceinline__ float ord2f(unsigned v) {
    unsigned u = (v & 0x80000000u) ? (v & 0x7fffffffu) : ~v;
    return __uint_as_float(u);
}
__device__ __forceinline__ unsigned short f2bf(float f) {   // RNE
    unsigned u = __float_as_uint(f);
    u += 0x7fffu + ((u >> 16) & 1u);
    return (unsigned short)(u >> 16);
}
__device__ __forceinline__ float bf2f(unsigned short h) {
    return __uint_as_float(((unsigned)h) << 16);
}

// ---------------------------------------------------------------------------
// C = A @ W^T + bias.  A: [4096,1024] rm, W: [1024,1024] rm.
// mode 0: out0 = fp32 [m][n]
// mode 1: out0 = fp32 headsplit [b,h,s,hd]
// mode 2: out0/out1 = bf16 hi/lo headsplit (split-bf16 for MFMA consumers)
// ---------------------------------------------------------------------------
__global__ __launch_bounds__(256)
void gemm_nt(const float* __restrict__ A, const float* __restrict__ W,
             const float* __restrict__ bias, void* __restrict__ out0,
             void* __restrict__ out1, int mode)
{
    __shared__ __align__(16) float As[16][132];
    __shared__ __align__(16) float Ws[16][68];
    const int tid = threadIdx.x;
    const int n0 = blockIdx.x * 64;
    const int m0 = blockIdx.y * 128;
    const int tx = tid & 15;
    const int ty = tid >> 4;

    float acc[8][4];
#pragma unroll
    for (int i = 0; i < 8; ++i)
#pragma unroll
        for (int j = 0; j < 4; ++j) acc[i][j] = 0.f;

    const int arow = tid >> 2;
    const int akq  = (tid & 3) * 4;

    for (int k0 = 0; k0 < 1024; k0 += 16) {
        const float4 av0 = *(const float4*)(A + (size_t)(m0 + arow) * 1024 + k0 + akq);
        const float4 av1 = *(const float4*)(A + (size_t)(m0 + arow + 64) * 1024 + k0 + akq);
        const float4 wv  = *(const float4*)(W + (size_t)(n0 + arow) * 1024 + k0 + akq);
        __syncthreads();
        As[akq + 0][arow] = av0.x; As[akq + 1][arow] = av0.y;
        As[akq + 2][arow] = av0.z; As[akq + 3][arow] = av0.w;
        As[akq + 0][arow + 64] = av1.x; As[akq + 1][arow + 64] = av1.y;
        As[akq + 2][arow + 64] = av1.z; As[akq + 3][arow + 64] = av1.w;
        Ws[akq + 0][arow] = wv.x; Ws[akq + 1][arow] = wv.y;
        Ws[akq + 2][arow] = wv.z; Ws[akq + 3][arow] = wv.w;
        __syncthreads();
#pragma unroll
        for (int kk = 0; kk < 16; ++kk) {
            const float4 a0 = *(const float4*)&As[kk][ty * 8];
            const float4 a1 = *(const float4*)&As[kk][ty * 8 + 4];
            const float4 bv = *(const float4*)&Ws[kk][tx * 4];
            const float a[8] = {a0.x, a0.y, a0.z, a0.w, a1.x, a1.y, a1.z, a1.w};
            const float b[4] = {bv.x, bv.y, bv.z, bv.w};
#pragma unroll
            for (int i = 0; i < 8; ++i)
#pragma unroll
                for (int j = 0; j < 4; ++j) acc[i][j] += a[i] * b[j];
        }
    }

    const int nb = n0 + tx * 4;
    const float4 b4 = *(const float4*)(bias + nb);
#pragma unroll
    for (int i = 0; i < 8; ++i) {
        const int m = m0 + ty * 8 + i;
        float o[4];
        o[0] = acc[i][0] + b4.x; o[1] = acc[i][1] + b4.y;
        o[2] = acc[i][2] + b4.z; o[3] = acc[i][3] + b4.w;
        if (mode == 0) {
            *(float4*)((float*)out0 + (size_t)m * 1024 + nb) = make_float4(o[0], o[1], o[2], o[3]);
        } else {
            const int b = m >> 11, s = m & 2047;
            const int h = nb >> 6, hd = nb & 63;
            const size_t base = ((size_t)((b * NH + h) * S_LEN + s)) * HDIM + hd;
            if (mode == 1) {
                *(float4*)((float*)out0 + base) = make_float4(o[0], o[1], o[2], o[3]);
            } else {
                ushort4 oh, ol;
                oh.x = f2bf(o[0]); ol.x = f2bf(o[0] - bf2f(oh.x));
                oh.y = f2bf(o[1]); ol.y = f2bf(o[1] - bf2f(oh.y));
                oh.z = f2bf(o[2]); ol.z = f2bf(o[2] - bf2f(oh.z));
                oh.w = f2bf(o[3]); ol.w = f2bf(o[3] - bf2f(oh.w));
                *(ushort4*)((unsigned short*)out0 + base) = oh;
                *(ushort4*)((unsigned short*)out1 + base) = ol;
            }
        }
    }
}

// ---------------------------------------------------------------------------
// V fp32 [bh][s][64] -> Vt bf16 [bh][64][2048]  (B-operand layout for PV MFMA)
// ---------------------------------------------------------------------------
__global__ __launch_bounds__(256)
void transpose_v(const float* __restrict__ V, unsigned short* __restrict__ Vt)
{
    __shared__ float t[64][65];
    const int tid = threadIdx.x;
    const int s0 = blockIdx.x * 64;
    const int bh = blockIdx.y;
    const float* Vb = V + (size_t)bh * S_LEN * HDIM;
#pragma unroll
    for (int i = 0; i < 4; ++i) {
        const int f = tid + i * 256;
        const int s = f >> 4;
        const int hq = (f & 15) * 4;
        const float4 v = *(const float4*)(Vb + (size_t)(s0 + s) * HDIM + hq);
        t[s][hq + 0] = v.x; t[s][hq + 1] = v.y; t[s][hq + 2] = v.z; t[s][hq + 3] = v.w;
    }
    __syncthreads();
    unsigned short* Vtb = Vt + (size_t)bh * HDIM * S_LEN;
#pragma unroll
    for (int i = 0; i < 4; ++i) {
        const int f = tid + i * 256;
        const int hd = f >> 4;
        const int sq = (f & 15) * 4;
        ushort4 o;
        o.x = f2bf(t[sq + 0][hd]); o.y = f2bf(t[sq + 1][hd]);
        o.z = f2bf(t[sq + 2][hd]); o.w = f2bf(t[sq + 3][hd]);
        *(ushort4*)(Vtb + (size_t)hd * S_LEN + s0 + sq) = o;
    }
}

// ---------------------------------------------------------------------------
// Exact 409th-largest over 2048 ordered uints held as u[32] per lane.
// ballot+popcount counting: 2 VALU + 2 SALU per element per bit, no shuffles.
// ---------------------------------------------------------------------------
__device__ __forceinline__ unsigned radix_select(const unsigned* u)
{
    unsigned T = 0;
    int rem = KK;
#pragma unroll 1
    for (int b = 31; b >= 0; --b) {
        const unsigned want = (T >> b) | 1u;
        int cnt = 0;
#pragma unroll
        for (int i = 0; i < 32; ++i)
            cnt += __builtin_popcountll(__ballot((u[i] >> b) == want));
        if (cnt >= rem) T |= (1u << b);
        else rem -= cnt;
    }
    return T;
}

// ---------------------------------------------------------------------------
// Fused attention v4: block = (b,h) x 16 q-rows, 512 threads (8 waves).
//  phase 1: scores via split-bf16 MFMA (3-pass), wave w keys [256w,256w+256)
//  phase 2: per-wave 2 rows: exact radix select (ballot-count) + exp -> P bf16
//  phase 3: dense PV via bf16 MFMA + cross-wave partial reduce
// LDS: sc fp32 [16][2052] (131.3 KB) overlaid after u-load by
//      P bf16 [16][2056] (64.3K) + Opart [8][16][64] f32 (32K); Q staging 4.5K.
// ---------------------------------------------------------------------------
__global__ __launch_bounds__(512, 1)
void attn_kernel(const unsigned short* __restrict__ Qh, const unsigned short* __restrict__ Ql,
                 const unsigned short* __restrict__ Kh, const unsigned short* __restrict__ Kl,
                 const unsigned short* __restrict__ Vt, float* __restrict__ AO)
{
    extern __shared__ __align__(16) char smem[];
    float* sc = (float*)smem;                                   // [16][SC_STR]
    unsigned short* P = (unsigned short*)smem;                  // overlay [16][P_STR]
    float* Opart = (float*)(smem + 66048);                      // [8][16][64]
    unsigned short* Qsh = (unsigned short*)(smem + 131328);     // [16][QS_STR]
    unsigned short* Qsl = (unsigned short*)(smem + 131328 + 2304);

    const int tid  = threadIdx.x;
    const int lane = tid & 63;
    const int w    = tid >> 6;
    const int q15  = lane & 15;
    const int quad = lane >> 4;

    // XCD swizzle: 4 heads per XCD -> K+V working set ~3 MB, fits 4 MB L2
    const int blk = blockIdx.x;
    const int bh  = (blk & 7) * 4 + ((blk >> 3) & 3);
    const int q0  = (blk >> 5) * 16;

    // ---- stage 16 Q rows (hi+lo bf16) into LDS ----
    if (tid < 256) {
        const int row = tid >> 4, dq = (tid & 15) * 4;
        const size_t g = ((size_t)bh * S_LEN + q0 + row) * HDIM + dq;
        *(ushort4*)(Qsh + row * QS_STR + dq) = *(const ushort4*)(Qh + g);
        *(ushort4*)(Qsl + row * QS_STR + dq) = *(const ushort4*)(Ql + g);
    }
    __syncthreads();

    // ---- phase 1: scores S^T[key][q] via split-bf16 MFMA ----
    {
        // B-frags (Q) hoisted: depend only on kstep
        const bf16x8 bqh0 = *(const bf16x8*)(Qsh + q15 * QS_STR + quad * 8);
        const bf16x8 bqh1 = *(const bf16x8*)(Qsh + q15 * QS_STR + 32 + quad * 8);
        const bf16x8 bql0 = *(const bf16x8*)(Qsl + q15 * QS_STR + quad * 8);
        const bf16x8 bql1 = *(const bf16x8*)(Qsl + q15 * QS_STR + 32 + quad * 8);
        const size_t kbase = (size_t)bh * S_LEN * HDIM;
#pragma unroll 4
        for (int t = 0; t < 16; ++t) {
            const int key = w * 256 + t * 16 + q15;    // A-frag m = lane&15
            const unsigned short* kh = Kh + kbase + (size_t)key * HDIM + quad * 8;
            const unsigned short* kl = Kl + kbase + (size_t)key * HDIM + quad * 8;
            const bf16x8 akh0 = *(const bf16x8*)(kh);
            const bf16x8 akh1 = *(const bf16x8*)(kh + 32);
            const bf16x8 akl0 = *(const bf16x8*)(kl);
            const bf16x8 akl1 = *(const bf16x8*)(kl + 32);
            f32x4 c = {0.f, 0.f, 0.f, 0.f};
            c = __builtin_amdgcn_mfma_f32_16x16x32_bf16(akh0, bqh0, c, 0, 0, 0);
            c = __builtin_amdgcn_mfma_f32_16x16x32_bf16(akh1, bqh1, c, 0, 0, 0);
            c = __builtin_amdgcn_mfma_f32_16x16x32_bf16(akh0, bql0, c, 0, 0, 0);
            c = __builtin_amdgcn_mfma_f32_16x16x32_bf16(akh1, bql1, c, 0, 0, 0);
            c = __builtin_amdgcn_mfma_f32_16x16x32_bf16(akl0, bqh0, c, 0, 0, 0);
            c = __builtin_amdgcn_mfma_f32_16x16x32_bf16(akl1, bqh1, c, 0, 0, 0);
            // C-layout: col=lane&15=q, row=quad*4+reg=key-in-tile
            const int key0 = w * 256 + t * 16 + quad * 4;
            f32x4 o = c * 0.125f;
            *(f32x4*)(sc + q15 * SC_STR + key0) = o;
        }
    }
    __syncthreads();

    // ---- load both owned rows into registers, then free the sc region ----
    const int r0 = 2 * w, r1 = 2 * w + 1;
    unsigned u0[32], u1[32];
#pragma unroll
    for (int i = 0; i < 32; ++i) u0[i] = f2ord(sc[r0 * SC_STR + i * 64 + lane]);
#pragma unroll
    for (int i = 0; i < 32; ++i) u1[i] = f2ord(sc[r1 * SC_STR + i * 64 + lane]);
    __syncthreads();   // sc dead; P/Opart region live

    // ---- phase 2: select + softmax numerators -> P (bf16), per row ----
    float invd[2];
#pragma unroll 1
    for (int rr = 0; rr < 2; ++rr) {
        const unsigned* u = rr ? u1 : u0;
        const int r = rr ? r1 : r0;
        const unsigned T = radix_select(u);
        unsigned umx = 0;
#pragma unroll
        for (int i = 0; i < 32; ++i) umx = u[i] > umx ? u[i] : umx;
#pragma unroll
        for (int off = 32; off >= 1; off >>= 1) {
            const unsigned o = (unsigned)__shfl_xor((int)umx, off);
            umx = o > umx ? o : umx;
        }
        const float mx = ord2f(umx);
        float lsum = 0.f;
        unsigned short* Pr = P + r * P_STR;
#pragma unroll
        for (int i = 0; i < 32; ++i) {
            const float e = (u[i] >= T) ? __expf(ord2f(u[i]) - mx) : 0.f;
            Pr[i * 64 + lane] = f2bf(e);
            lsum += e;
        }
#pragma unroll
        for (int off = 32; off >= 1; off >>= 1) lsum += __shfl_xor(lsum, off);
        invd[rr] = 1.f / lsum;
    }
    __syncthreads();   // all P visible

    // ---- phase 3: dense PV via bf16 MFMA, wave w keys [256w,256w+256) ----
    {
        f32x4 oacc[4];
#pragma unroll
        for (int ht = 0; ht < 4; ++ht) oacc[ht] = (f32x4){0.f, 0.f, 0.f, 0.f};
        const size_t vtb = (size_t)bh * HDIM * S_LEN;
#pragma unroll 2
        for (int ks = 0; ks < 8; ++ks) {
            const int key0 = w * 256 + ks * 32 + quad * 8;
            const bf16x8 ap = *(const bf16x8*)(P + q15 * P_STR + key0);  // A[m=q][k=key]
#pragma unroll
            for (int ht = 0; ht < 4; ++ht) {
                const int hd = ht * 16 + q15;                            // B[k=key][n=hd]
                const bf16x8 bv = *(const bf16x8*)(Vt + vtb + (size_t)hd * S_LEN + key0);
                oacc[ht] = __builtin_amdgcn_mfma_f32_16x16x32_bf16(ap, bv, oacc[ht], 0, 0, 0);
            }
        }
        // D[m=q][n=hd]: col=lane&15=hd-in-tile, row=quad*4+reg=q
#pragma unroll
        for (int ht = 0; ht < 4; ++ht)
#pragma unroll
            for (int rg = 0; rg < 4; ++rg)
                Opart[w * 1024 + (quad * 4 + rg) * 64 + ht * 16 + q15] = oacc[ht][rg];
    }
    __syncthreads();

    // ---- final: reduce 8 partials, scale by invd, write AO fp32 ----
    {
        float s0 = 0.f, s1 = 0.f;
#pragma unroll
        for (int ww = 0; ww < 8; ++ww) {
            s0 += Opart[ww * 1024 + r0 * 64 + lane];
            s1 += Opart[ww * 1024 + r1 * 64 + lane];
        }
        const int b = bh >> 4, h = bh & 15;
        AO[((size_t)(b * S_LEN + q0 + r0)) * DMODEL + h * HDIM + lane] = s0 * invd[0];
        AO[((size_t)(b * S_LEN + q0 + r1)) * DMODEL + h * HDIM + lane] = s1 * invd[1];
    }
}

// ---------------------------------------------------------------------------
extern "C" void kernel_launch(void* const* d_in, const int* in_sizes, int n_in,
                              void* d_out, int out_size, void* d_ws, size_t ws_size,
                              hipStream_t stream)
{
    const float* X  = (const float*)d_in[0];
    const float* Wq = (const float*)d_in[1];
    const float* bq = (const float*)d_in[2];
    const float* Wk = (const float*)d_in[3];
    const float* bk = (const float*)d_in[4];
    const float* Wv = (const float*)d_in[5];
    const float* bv = (const float*)d_in[6];
    const float* Wo = (const float*)d_in[7];
    const float* bo = (const float*)d_in[8];

    char* p = (char*)d_ws;
    const size_t NEL = (size_t)BHC * S_LEN * HDIM;   // 4,194,304
    unsigned short* Q16h = (unsigned short*)p; p += NEL * 2;
    unsigned short* Q16l = (unsigned short*)p; p += NEL * 2;
    unsigned short* K16h = (unsigned short*)p; p += NEL * 2;
    unsigned short* K16l = (unsigned short*)p; p += NEL * 2;
    float*          Vf   = (float*)p;          p += NEL * 4;
    unsigned short* Vt16 = (unsigned short*)p; p += NEL * 2;
    float*          AO   = (float*)p;          p += NEL * 4;   // [B,S,D]

    const int attn_lds = 131328 + 2 * 2304;   // 135,936 B
    hipFuncSetAttribute((const void*)attn_kernel,
                        hipFuncAttributeMaxDynamicSharedMemorySize, attn_lds);

    const dim3 ggrid(16, 32, 1);
    gemm_nt<<<ggrid, 256, 0, stream>>>(X, Wq, bq, Q16h, Q16l, 2);
    gemm_nt<<<ggrid, 256, 0, stream>>>(X, Wk, bk, K16h, K16l, 2);
    gemm_nt<<<ggrid, 256, 0, stream>>>(X, Wv, bv, Vf, nullptr, 1);
    transpose_v<<<dim3(32, 32, 1), 256, 0, stream>>>(Vf, Vt16);
    attn_kernel<<<4096, 512, attn_lds, stream>>>(Q16h, Q16l, K16h, K16l, Vt16, AO);
    gemm_nt<<<ggrid, 256, 0, stream>>>(AO, Wo, bo, d_out, nullptr, 0);
}

// Round 5
// 1154.592 us; speedup vs baseline: 1.8803x; 1.2800x over previous
//
#include <hip/hip_runtime.h>
#include <math.h>

#define S_LEN 2048
#define NH 16
#define HDIM 64
#define BATCH 2
#define BHC 32          // BATCH*NH
#define KK 409          // int(2048 * (1.0 - 0.8)) per reference float math
#define DMODEL 1024

typedef __attribute__((ext_vector_type(8))) short bf16x8;   // 8 bf16 in 4 VGPRs
typedef __attribute__((ext_vector_type(4))) float f32x4;

#define SC_STR 1032     // fp32 half-score row stride (chunked exchange)
#define P_STR  2056     // bf16 P row stride (16B-aligned rows)

__device__ __forceinline__ unsigned f2ord(float f) {
    unsigned u = __float_as_uint(f);
    return (u & 0x80000000u) ? ~u : (u | 0x80000000u);
}
__device__ __forceinline__ float ord2f(unsigned v) {
    unsigned u = (v & 0x80000000u) ? (v & 0x7fffffffu) : ~v;
    return __uint_as_float(u);
}
__device__ __forceinline__ unsigned short f2bf(float f) {   // RNE
    unsigned u = __float_as_uint(f);
    u += 0x7fffu + ((u >> 16) & 1u);
    return (unsigned short)(u >> 16);
}
__device__ __forceinline__ float bf2f(unsigned short h) {
    return __uint_as_float(((unsigned)h) << 16);
}

// ---------------------------------------------------------------------------
// C = A @ W^T + bias.  A: [4096,1024] rm, W: [1024,1024] rm.
// mode 0: out0 = fp32 [m][n]
// mode 1: out0 = fp32 headsplit [b,h,s,hd]
// mode 2: out0/out1 = bf16 hi/lo headsplit (split-bf16 for MFMA consumers)
// ---------------------------------------------------------------------------
__global__ __launch_bounds__(256)
void gemm_nt(const float* __restrict__ A, const float* __restrict__ W,
             const float* __restrict__ bias, void* __restrict__ out0,
             void* __restrict__ out1, int mode)
{
    __shared__ __align__(16) float As[16][132];
    __shared__ __align__(16) float Ws[16][68];
    const int tid = threadIdx.x;
    const int n0 = blockIdx.x * 64;
    const int m0 = blockIdx.y * 128;
    const int tx = tid & 15;
    const int ty = tid >> 4;

    float acc[8][4];
#pragma unroll
    for (int i = 0; i < 8; ++i)
#pragma unroll
        for (int j = 0; j < 4; ++j) acc[i][j] = 0.f;

    const int arow = tid >> 2;
    const int akq  = (tid & 3) * 4;

    for (int k0 = 0; k0 < 1024; k0 += 16) {
        const float4 av0 = *(const float4*)(A + (size_t)(m0 + arow) * 1024 + k0 + akq);
        const float4 av1 = *(const float4*)(A + (size_t)(m0 + arow + 64) * 1024 + k0 + akq);
        const float4 wv  = *(const float4*)(W + (size_t)(n0 + arow) * 1024 + k0 + akq);
        __syncthreads();
        As[akq + 0][arow] = av0.x; As[akq + 1][arow] = av0.y;
        As[akq + 2][arow] = av0.z; As[akq + 3][arow] = av0.w;
        As[akq + 0][arow + 64] = av1.x; As[akq + 1][arow + 64] = av1.y;
        As[akq + 2][arow + 64] = av1.z; As[akq + 3][arow + 64] = av1.w;
        Ws[akq + 0][arow] = wv.x; Ws[akq + 1][arow] = wv.y;
        Ws[akq + 2][arow] = wv.z; Ws[akq + 3][arow] = wv.w;
        __syncthreads();
#pragma unroll
        for (int kk = 0; kk < 16; ++kk) {
            const float4 a0 = *(const float4*)&As[kk][ty * 8];
            const float4 a1 = *(const float4*)&As[kk][ty * 8 + 4];
            const float4 bv = *(const float4*)&Ws[kk][tx * 4];
            const float a[8] = {a0.x, a0.y, a0.z, a0.w, a1.x, a1.y, a1.z, a1.w};
            const float b[4] = {bv.x, bv.y, bv.z, bv.w};
#pragma unroll
            for (int i = 0; i < 8; ++i)
#pragma unroll
                for (int j = 0; j < 4; ++j) acc[i][j] += a[i] * b[j];
        }
    }

    const int nb = n0 + tx * 4;
    const float4 b4 = *(const float4*)(bias + nb);
#pragma unroll
    for (int i = 0; i < 8; ++i) {
        const int m = m0 + ty * 8 + i;
        float o[4];
        o[0] = acc[i][0] + b4.x; o[1] = acc[i][1] + b4.y;
        o[2] = acc[i][2] + b4.z; o[3] = acc[i][3] + b4.w;
        if (mode == 0) {
            *(float4*)((float*)out0 + (size_t)m * 1024 + nb) = make_float4(o[0], o[1], o[2], o[3]);
        } else {
            const int b = m >> 11, s = m & 2047;
            const int h = nb >> 6, hd = nb & 63;
            const size_t base = ((size_t)((b * NH + h) * S_LEN + s)) * HDIM + hd;
            if (mode == 1) {
                *(float4*)((float*)out0 + base) = make_float4(o[0], o[1], o[2], o[3]);
            } else {
                ushort4 oh, ol;
                oh.x = f2bf(o[0]); ol.x = f2bf(o[0] - bf2f(oh.x));
                oh.y = f2bf(o[1]); ol.y = f2bf(o[1] - bf2f(oh.y));
                oh.z = f2bf(o[2]); ol.z = f2bf(o[2] - bf2f(oh.z));
                oh.w = f2bf(o[3]); ol.w = f2bf(o[3] - bf2f(oh.w));
                *(ushort4*)((unsigned short*)out0 + base) = oh;
                *(ushort4*)((unsigned short*)out1 + base) = ol;
            }
        }
    }
}

// ---------------------------------------------------------------------------
// V fp32 [bh][s][64] -> Vt bf16 [bh][64][2048]  (B-operand layout for PV MFMA)
// ---------------------------------------------------------------------------
__global__ __launch_bounds__(256)
void transpose_v(const float* __restrict__ V, unsigned short* __restrict__ Vt)
{
    __shared__ float t[64][65];
    const int tid = threadIdx.x;
    const int s0 = blockIdx.x * 64;
    const int bh = blockIdx.y;
    const float* Vb = V + (size_t)bh * S_LEN * HDIM;
#pragma unroll
    for (int i = 0; i < 4; ++i) {
        const int f = tid + i * 256;
        const int s = f >> 4;
        const int hq = (f & 15) * 4;
        const float4 v = *(const float4*)(Vb + (size_t)(s0 + s) * HDIM + hq);
        t[s][hq + 0] = v.x; t[s][hq + 1] = v.y; t[s][hq + 2] = v.z; t[s][hq + 3] = v.w;
    }
    __syncthreads();
    unsigned short* Vtb = Vt + (size_t)bh * HDIM * S_LEN;
#pragma unroll
    for (int i = 0; i < 4; ++i) {
        const int f = tid + i * 256;
        const int hd = f >> 4;
        const int sq = (f & 15) * 4;
        ushort4 o;
        o.x = f2bf(t[sq + 0][hd]); o.y = f2bf(t[sq + 1][hd]);
        o.z = f2bf(t[sq + 2][hd]); o.w = f2bf(t[sq + 3][hd]);
        *(ushort4*)(Vtb + (size_t)hd * S_LEN + s0 + sq) = o;
    }
}

// ---------------------------------------------------------------------------
// Exact 409th-largest over 2048 ordered uints held as u[32] per lane.
// ballot+popcount counting; early exit: when candidate count == rem, the
// answer is min over candidates (gap C-rem halves on every set bit).
// ---------------------------------------------------------------------------
__device__ __forceinline__ unsigned radix_select(const unsigned* u)
{
    unsigned T = 0;
    int rem = KK;
    int C = 2048;
#pragma unroll 1
    for (int b = 31; b >= 0; --b) {
        const unsigned want = (T >> b) | 1u;
        int cnt = 0;
#pragma unroll
        for (int i = 0; i < 32; ++i)
            cnt += __builtin_popcountll(__ballot((u[i] >> b) == want));
        if (cnt >= rem) { T |= (1u << b); C = cnt; }
        else { rem -= cnt; C -= cnt; }
        if (C == rem) {   // k-th largest = min over current candidate set
            const unsigned pre = T >> b;
            unsigned mn = 0xffffffffu;
#pragma unroll
            for (int i = 0; i < 32; ++i) {
                const unsigned v = ((u[i] >> b) == pre) ? u[i] : 0xffffffffu;
                mn = v < mn ? v : mn;
            }
#pragma unroll
            for (int off = 32; off >= 1; off >>= 1) {
                const unsigned o = (unsigned)__shfl_xor((int)mn, off);
                mn = o < mn ? o : mn;
            }
            return mn;
        }
    }
    return T;
}

// ---------------------------------------------------------------------------
// Fused attention v5: block = (b,h) x 16 q-rows, 512 threads (8 waves).
//  phase 1: scores via split-bf16 MFMA, exchanged through a HALF-SIZE LDS
//           buffer in two key-chunks (other half parked in accumulator regs)
//  phase 2: per-wave 2 rows: exact radix select (early-exit) + exp -> P bf16
//  phase 3: dense PV via bf16 MFMA + cross-wave partial reduce
// LDS: 66 KB (sc-chunk [16][1032] f32, overlaid by P [16][2056] bf16 and
// Opart [8][16][64] f32) -> 2 blocks/CU, 4 waves/SIMD.
// ---------------------------------------------------------------------------
__global__ __launch_bounds__(512, 4)
void attn_kernel(const unsigned short* __restrict__ Qh, const unsigned short* __restrict__ Ql,
                 const unsigned short* __restrict__ Kh, const unsigned short* __restrict__ Kl,
                 const unsigned short* __restrict__ Vt, float* __restrict__ AO)
{
    extern __shared__ __align__(16) char smem[];
    float* sc = (float*)smem;                       // [16][SC_STR] chunk, 66048 B
    unsigned short* P = (unsigned short*)smem;      // overlay [16][P_STR], 65792 B
    float* Opart = (float*)smem;                    // overlay [8][16][64], 32768 B

    const int tid  = threadIdx.x;
    const int lane = tid & 63;
    const int w    = tid >> 6;
    const int q15  = lane & 15;
    const int quad = lane >> 4;

    // XCD swizzle: 4 heads per XCD -> K+V working set ~2.5 MB, fits 4 MB L2
    const int blk = blockIdx.x;
    const int bh  = (blk & 7) * 4 + ((blk >> 3) & 3);
    const int q0  = (blk >> 5) * 16;

    // ---- Q B-frags direct from global (held in regs for both chunks) ----
    const size_t qrow = ((size_t)bh * S_LEN + q0 + q15) * HDIM;
    const bf16x8 bqh0 = *(const bf16x8*)(Qh + qrow + quad * 8);
    const bf16x8 bqh1 = *(const bf16x8*)(Qh + qrow + 32 + quad * 8);
    const bf16x8 bql0 = *(const bf16x8*)(Ql + qrow + quad * 8);
    const bf16x8 bql1 = *(const bf16x8*)(Ql + qrow + 32 + quad * 8);

    const size_t kbase = (size_t)bh * S_LEN * HDIM;
    const int r0 = 2 * w, r1 = 2 * w + 1;
    unsigned u0[32], u1[32];

    // ---- phase 1: two key-chunks through the half-size exchange buffer ----
#pragma unroll 1
    for (int half = 0; half < 2; ++half) {
        f32x4 acc[8];
#pragma unroll 2
        for (int t = 0; t < 8; ++t) {
            const int key = w * 256 + half * 128 + t * 16 + q15;   // A-frag m
            const unsigned short* kh = Kh + kbase + (size_t)key * HDIM + quad * 8;
            const unsigned short* kl = Kl + kbase + (size_t)key * HDIM + quad * 8;
            const bf16x8 akh0 = *(const bf16x8*)(kh);
            const bf16x8 akh1 = *(const bf16x8*)(kh + 32);
            const bf16x8 akl0 = *(const bf16x8*)(kl);
            const bf16x8 akl1 = *(const bf16x8*)(kl + 32);
            f32x4 c = {0.f, 0.f, 0.f, 0.f};
            c = __builtin_amdgcn_mfma_f32_16x16x32_bf16(akh0, bqh0, c, 0, 0, 0);
            c = __builtin_amdgcn_mfma_f32_16x16x32_bf16(akh1, bqh1, c, 0, 0, 0);
            c = __builtin_amdgcn_mfma_f32_16x16x32_bf16(akh0, bql0, c, 0, 0, 0);
            c = __builtin_amdgcn_mfma_f32_16x16x32_bf16(akh1, bql1, c, 0, 0, 0);
            c = __builtin_amdgcn_mfma_f32_16x16x32_bf16(akl0, bqh0, c, 0, 0, 0);
            c = __builtin_amdgcn_mfma_f32_16x16x32_bf16(akl1, bqh1, c, 0, 0, 0);
            acc[t] = c * 0.125f;
        }
        if (half) __syncthreads();   // chunk-A reads complete before overwrite
        // C-layout: col=lane&15=q, row-in-tile=quad*4+reg=key
        // chunk col c = w*128 + t*16 + quad*4 (+reg); actual key = c + 128*(c>>7) + 128*half
#pragma unroll
        for (int t = 0; t < 8; ++t)
            *(f32x4*)(sc + q15 * SC_STR + w * 128 + t * 16 + quad * 4) = acc[t];
        __syncthreads();
        // read both owned rows' half (strided: bank = lane%32, 2-way free)
        unsigned* d0 = u0 + half * 16;
        unsigned* d1 = u1 + half * 16;
#pragma unroll
        for (int i = 0; i < 16; ++i) d0[i] = f2ord(sc[r0 * SC_STR + i * 64 + lane]);
#pragma unroll
        for (int i = 0; i < 16; ++i) d1[i] = f2ord(sc[r1 * SC_STR + i * 64 + lane]);
    }
    __syncthreads();   // all chunk reads done; sc region is dead -> P region live

    // ---- phase 2: select + softmax numerators -> P (bf16), 2 rows/wave ----
    float invd[2];
#pragma unroll 1
    for (int rr = 0; rr < 2; ++rr) {
        const unsigned* u = rr ? u1 : u0;
        const int r = rr ? r1 : r0;
        const unsigned T = radix_select(u);
        unsigned umx = 0;
#pragma unroll
        for (int i = 0; i < 32; ++i) umx = u[i] > umx ? u[i] : umx;
#pragma unroll
        for (int off = 32; off >= 1; off >>= 1) {
            const unsigned o = (unsigned)__shfl_xor((int)umx, off);
            umx = o > umx ? o : umx;
        }
        const float mx = ord2f(umx);
        float lsum = 0.f;
        unsigned short* Pr = P + r * P_STR;
#pragma unroll
        for (int i = 0; i < 32; ++i) {
            // chunk col -> actual key: ii = i&15; key = ii*64 + (ii>>1)*128 + (i>>4)*128 + lane
            const int ii = i & 15;
            const int kb = ii * 64 + (ii >> 1) * 128 + (i >> 4) * 128;
            const float e = (u[i] >= T) ? __expf(ord2f(u[i]) - mx) : 0.f;
            Pr[kb + lane] = f2bf(e);
            lsum += e;
        }
#pragma unroll
        for (int off = 32; off >= 1; off >>= 1) lsum += __shfl_xor(lsum, off);
        invd[rr] = 1.f / lsum;
    }
    __syncthreads();   // all P visible

    // ---- phase 3: dense PV via bf16 MFMA, wave w keys [256w,256w+256) ----
    {
        f32x4 oacc[4];
#pragma unroll
        for (int ht = 0; ht < 4; ++ht) oacc[ht] = (f32x4){0.f, 0.f, 0.f, 0.f};
        const size_t vtb = (size_t)bh * HDIM * S_LEN;
#pragma unroll 2
        for (int ks = 0; ks < 8; ++ks) {
            const int key0 = w * 256 + ks * 32 + quad * 8;
            const bf16x8 ap = *(const bf16x8*)(P + q15 * P_STR + key0);  // A[m=q][k=key]
#pragma unroll
            for (int ht = 0; ht < 4; ++ht) {
                const int hd = ht * 16 + q15;                            // B[k=key][n=hd]
                const bf16x8 bv = *(const bf16x8*)(Vt + vtb + (size_t)hd * S_LEN + key0);
                oacc[ht] = __builtin_amdgcn_mfma_f32_16x16x32_bf16(ap, bv, oacc[ht], 0, 0, 0);
            }
        }
        __syncthreads();   // all P reads done; P region dead -> Opart live
        // D[m=q][n=hd]: col=lane&15=hd-in-tile, row=quad*4+reg=q
#pragma unroll
        for (int ht = 0; ht < 4; ++ht)
#pragma unroll
            for (int rg = 0; rg < 4; ++rg)
                Opart[w * 1024 + (quad * 4 + rg) * 64 + ht * 16 + q15] = oacc[ht][rg];
    }
    __syncthreads();

    // ---- final: reduce 8 partials, scale by invd, write AO fp32 ----
    {
        float s0 = 0.f, s1 = 0.f;
#pragma unroll
        for (int ww = 0; ww < 8; ++ww) {
            s0 += Opart[ww * 1024 + r0 * 64 + lane];
            s1 += Opart[ww * 1024 + r1 * 64 + lane];
        }
        const int b = bh >> 4, h = bh & 15;
        AO[((size_t)(b * S_LEN + q0 + r0)) * DMODEL + h * HDIM + lane] = s0 * invd[0];
        AO[((size_t)(b * S_LEN + q0 + r1)) * DMODEL + h * HDIM + lane] = s1 * invd[1];
    }
}

// ---------------------------------------------------------------------------
extern "C" void kernel_launch(void* const* d_in, const int* in_sizes, int n_in,
                              void* d_out, int out_size, void* d_ws, size_t ws_size,
                              hipStream_t stream)
{
    const float* X  = (const float*)d_in[0];
    const float* Wq = (const float*)d_in[1];
    const float* bq = (const float*)d_in[2];
    const float* Wk = (const float*)d_in[3];
    const float* bk = (const float*)d_in[4];
    const float* Wv = (const float*)d_in[5];
    const float* bv = (const float*)d_in[6];
    const float* Wo = (const float*)d_in[7];
    const float* bo = (const float*)d_in[8];

    char* p = (char*)d_ws;
    const size_t NEL = (size_t)BHC * S_LEN * HDIM;   // 4,194,304
    unsigned short* Q16h = (unsigned short*)p; p += NEL * 2;
    unsigned short* Q16l = (unsigned short*)p; p += NEL * 2;
    unsigned short* K16h = (unsigned short*)p; p += NEL * 2;
    unsigned short* K16l = (unsigned short*)p; p += NEL * 2;
    float*          Vf   = (float*)p;          p += NEL * 4;
    unsigned short* Vt16 = (unsigned short*)p; p += NEL * 2;
    float*          AO   = (float*)p;          p += NEL * 4;   // [B,S,D]

    const int attn_lds = 16 * SC_STR * 4;   // 66,048 B
    hipFuncSetAttribute((const void*)attn_kernel,
                        hipFuncAttributeMaxDynamicSharedMemorySize, attn_lds);

    const dim3 ggrid(16, 32, 1);
    gemm_nt<<<ggrid, 256, 0, stream>>>(X, Wq, bq, Q16h, Q16l, 2);
    gemm_nt<<<ggrid, 256, 0, stream>>>(X, Wk, bk, K16h, K16l, 2);
    gemm_nt<<<ggrid, 256, 0, stream>>>(X, Wv, bv, Vf, nullptr, 1);
    transpose_v<<<dim3(32, 32, 1), 256, 0, stream>>>(Vf, Vt16);
    attn_kernel<<<4096, 512, attn_lds, stream>>>(Q16h, Q16l, K16h, K16l, Vt16, AO);
    gemm_nt<<<ggrid, 256, 0, stream>>>(AO, Wo, bo, d_out, nullptr, 0);
}